// Round 1
// baseline (623.238 us; speedup 1.0000x reference)
//
#include <hip/hip_runtime.h>
#include <math.h>

#define LL 8192
#define NLAYERS 4
#define NSTATE 64
#define SQ2H 0.70710678118654752f
#define PI_D 3.14159265358979323846

__device__ __forceinline__ float2 cmulf(float2 a, float2 b) {
  return make_float2(a.x*b.x - a.y*b.y, a.x*b.y + a.y*b.x);
}
__device__ __forceinline__ float2 caddf(float2 a, float2 b) { return make_float2(a.x+b.x, a.y+b.y); }
__device__ __forceinline__ float2 csubf(float2 a, float2 b) { return make_float2(a.x-b.x, a.y-b.y); }
__device__ __forceinline__ float2 cconjf(float2 a) { return make_float2(a.x, -a.y); }
__device__ __forceinline__ float2 cmuli(float2 a)  { return make_float2(-a.y, a.x); }  // * +i
__device__ __forceinline__ float2 cmulni(float2 a) { return make_float2(a.y, -a.x); }  // * -i

// d * e^{-i pi k/4}
__device__ __forceinline__ float2 mulC8(float2 d, int k) {
  switch (k & 3) {
    case 0: return d;
    case 1: return make_float2(SQ2H*(d.x + d.y), SQ2H*(d.y - d.x));
    case 2: return cmulni(d);
    default: return make_float2(SQ2H*(d.y - d.x), -SQ2H*(d.x + d.y));
  }
}
// d * e^{+i pi k/4}
__device__ __forceinline__ float2 mulC8c(float2 d, int k) {
  switch (k & 3) {
    case 0: return d;
    case 1: return make_float2(SQ2H*(d.x - d.y), SQ2H*(d.x + d.y));
    case 2: return cmuli(d);
    default: return make_float2(-SQ2H*(d.x + d.y), SQ2H*(d.x - d.y));
  }
}
// d * e^{-i pi j/8}, j in [0,8)
__device__ __forceinline__ float2 mulC16(float2 d, int j) {
  if (j == 0) return d;
  if (j == 2) return make_float2(SQ2H*(d.x + d.y), SQ2H*(d.y - d.x));
  if (j == 4) return cmulni(d);
  if (j == 6) return make_float2(SQ2H*(d.y - d.x), -SQ2H*(d.x + d.y));
  const float C1 = 0.92387953251128674f, S1 = 0.38268343236508978f;
  float cc, ss;
  if (j == 1)      { cc =  C1; ss = -S1; }
  else if (j == 3) { cc =  S1; ss = -C1; }
  else if (j == 5) { cc = -S1; ss = -C1; }
  else             { cc = -C1; ss = -S1; }
  return make_float2(d.x*cc - d.y*ss, d.x*ss + d.y*cc);
}
// d * e^{+i pi j/8}
__device__ __forceinline__ float2 mulC16c(float2 d, int j) {
  if (j == 0) return d;
  if (j == 2) return make_float2(SQ2H*(d.x - d.y), SQ2H*(d.x + d.y));
  if (j == 4) return cmuli(d);
  if (j == 6) return make_float2(-SQ2H*(d.x + d.y), SQ2H*(d.x - d.y));
  const float C1 = 0.92387953251128674f, S1 = 0.38268343236508978f;
  float cc, ss;
  if (j == 1)      { cc =  C1; ss =  S1; }
  else if (j == 3) { cc =  S1; ss =  C1; }
  else if (j == 5) { cc = -S1; ss =  C1; }
  else             { cc = -C1; ss =  S1; }
  return make_float2(d.x*cc - d.y*ss, d.x*ss + d.y*cc);
}

// 3 forward DIF stages (sizes 8S,4S,2S) on 16 elems {r+c + S*k}, T1[c]=W_{8S}^{r+c}
__device__ __forceinline__ void dif3(float2 v[8][2], const float2* T1) {
#pragma unroll
  for (int c = 0; c < 2; c++) {
    const float2 t1 = T1[c];
    const float2 t2 = cmulf(t1, t1);
    const float2 t4 = cmulf(t2, t2);
#pragma unroll
    for (int k = 0; k < 4; k++) {           // m=8S: (k,k+4), tw = t1*C8[k]
      float2 a = v[k][c], b = v[k+4][c];
      float2 d = csubf(a, b);
      v[k][c] = caddf(a, b);
      v[k+4][c] = cmulf(mulC8(d, k), t1);
    }
#pragma unroll
    for (int h = 0; h < 8; h += 4)          // m=4S: (k,k+2), tw = t2*{1,-i}
#pragma unroll
      for (int l = 0; l < 2; l++) {
        int k = h + l;
        float2 a = v[k][c], b = v[k+2][c];
        float2 d = csubf(a, b);
        v[k][c] = caddf(a, b);
        float2 e = cmulf(d, t2);
        v[k+2][c] = (l == 0) ? e : cmulni(e);
      }
#pragma unroll
    for (int k = 0; k < 8; k += 2) {        // m=2S: (k,k+1), tw = t4
      float2 a = v[k][c], b = v[k+1][c];
      v[k][c] = caddf(a, b);
      v[k+1][c] = cmulf(csubf(a, b), t4);
    }
  }
}

// 3 inverse DIT stages (sizes m1,2m1,4m1), U1[c]=W_{4m1}^{-(r+c)}
__device__ __forceinline__ void dit3(float2 v[8][2], const float2* U1) {
#pragma unroll
  for (int c = 0; c < 2; c++) {
    const float2 u1 = U1[c];
    const float2 u2 = cmulf(u1, u1);
    const float2 u4 = cmulf(u2, u2);
#pragma unroll
    for (int k = 0; k < 8; k += 2) {        // m1: (k,k+1), tw = u4
      float2 a = v[k][c];
      float2 b = cmulf(v[k+1][c], u4);
      v[k][c] = caddf(a, b);
      v[k+1][c] = csubf(a, b);
    }
#pragma unroll
    for (int h = 0; h < 8; h += 4)          // 2m1: (k,k+2), tw = u2*{1,+i}
#pragma unroll
      for (int l = 0; l < 2; l++) {
        int k = h + l;
        float2 a = v[k][c];
        float2 b = cmulf(v[k+2][c], u2);
        if (l == 1) b = cmuli(b);
        v[k][c] = caddf(a, b);
        v[k+2][c] = csubf(a, b);
      }
#pragma unroll
    for (int k = 0; k < 4; k++) {           // 4m1: (k,k+4), tw = u1*conjC8[k]
      float2 a = v[k][c];
      float2 b = mulC8c(cmulf(v[k+4][c], u1), k);
      v[k][c] = caddf(a, b);
      v[k+4][c] = csubf(a, b);
    }
  }
}

// forward stages m=16,8,4,2 on 16 contiguous elems (const twiddles only)
__device__ __forceinline__ void fwd4(float2 w[16]) {
#pragma unroll
  for (int j = 0; j < 8; j++) {
    float2 a = w[j], b = w[j+8];
    w[j] = caddf(a, b);
    w[j+8] = mulC16(csubf(a, b), j);
  }
#pragma unroll
  for (int h = 0; h < 16; h += 8)
#pragma unroll
    for (int l = 0; l < 4; l++) {
      int j = h + l;
      float2 a = w[j], b = w[j+4];
      w[j] = caddf(a, b);
      w[j+4] = mulC8(csubf(a, b), l);
    }
#pragma unroll
  for (int h = 0; h < 16; h += 4)
#pragma unroll
    for (int l = 0; l < 2; l++) {
      int j = h + l;
      float2 a = w[j], b = w[j+2];
      float2 d = csubf(a, b);
      w[j] = caddf(a, b);
      w[j+2] = (l == 0) ? d : cmulni(d);
    }
#pragma unroll
  for (int j = 0; j < 16; j += 2) {
    float2 a = w[j], b = w[j+1];
    w[j] = caddf(a, b);
    w[j+1] = csubf(a, b);
  }
}

// inverse stages m=2,4,8,16 on 16 contiguous elems
__device__ __forceinline__ void inv4(float2 w[16]) {
#pragma unroll
  for (int j = 0; j < 16; j += 2) {
    float2 a = w[j], b = w[j+1];
    w[j] = caddf(a, b);
    w[j+1] = csubf(a, b);
  }
#pragma unroll
  for (int h = 0; h < 16; h += 4)
#pragma unroll
    for (int l = 0; l < 2; l++) {
      int j = h + l;
      float2 a = w[j], b = w[j+2];
      if (l == 1) b = cmuli(b);
      w[j] = caddf(a, b);
      w[j+2] = csubf(a, b);
    }
#pragma unroll
  for (int h = 0; h < 16; h += 8)
#pragma unroll
    for (int l = 0; l < 4; l++) {
      int j = h + l;
      float2 a = w[j], b = mulC8c(w[j+4], l);
      w[j] = caddf(a, b);
      w[j+4] = csubf(a, b);
    }
#pragma unroll
  for (int j = 0; j < 8; j++) {
    float2 a = w[j], b = mulC16c(w[j+8], j);
    w[j] = caddf(a, b);
    w[j+8] = csubf(a, b);
  }
}

__device__ __forceinline__ float gelu_exact(float x) {
  return 0.5f * x * (1.0f + erff(x * 0.70710678118654752f));
}

// ---- setup: Khp_br[layer][bitrev13(f)] = (Kh(f)+1)/L in fp64, Kh = Hermitian part of K
__global__ void ssm_setup(const float* __restrict__ Lr, const float* __restrict__ Li,
                          const float* __restrict__ Pv, const float* __restrict__ Bv,
                          const float* __restrict__ Cv, const float* __restrict__ Sv,
                          float2* __restrict__ khp) {
  const int f = blockIdx.x * blockDim.x + threadIdx.x;
  const int layer = blockIdx.y;
  if (f >= LL) return;
  const double step = (double)Sv[layer];
  const float* lr = Lr + layer * NSTATE;
  const float* li = Li + layer * NSTATE;
  const float* pp = Pv + layer * NSTATE;
  const float* bb = Bv + layer * NSTATE;
  const float* ct = Cv + layer * NSTATE;

  double Kr[2], Ki[2];
  const int f2[2] = { f, (LL - f) & (LL - 1) };
#pragma unroll 1
  for (int s = 0; s < 2; s++) {
    const double th = -2.0 * PI_D * (double)f2[s] / (double)LL;
    const double co = cos(th), si = sin(th);
    const double pr = 1.0 + co, pim = si;
    const double pd = pr*pr + pim*pim;
    const double cr = 2.0*pr/pd, ci = -2.0*pim/pd;          // c = 2/(1+Om)
    const double mr = 1.0 - co, mi = -si;
    const double ts = 2.0 / step;
    const double gr = ts*(mr*pr + mi*pim)/pd;               // g = ts*(1-Om)/(1+Om)
    const double gi = ts*(mi*pr - mr*pim)/pd;
    double k00r=0,k00i=0,k01r=0,k01i=0,k10r=0,k10i=0,k11r=0,k11i=0;
    for (int n = 0; n < NSTATE; n++) {
      const double dr = gr - (double)lr[n];
      const double di = gi - (double)li[n];
      const double dd = dr*dr + di*di;
      const double ir = dr/dd, ii = -di/dd;                 // 1/denom
      const double p = (double)pp[n], b = (double)bb[n], c = (double)ct[n];
      double w;
      w = c*b; k00r += w*ir; k00i += w*ii;
      w = c*p; k01r += w*ir; k01i += w*ii;
      w = p*b; k10r += w*ir; k10i += w*ii;
      w = p*p; k11r += w*ir; k11i += w*ii;
    }
    const double ar = k01r*k10r - k01i*k10i;
    const double ai = k01r*k10i + k01i*k10r;
    const double qr = 1.0 + k11r, qi = k11i;
    const double qd = qr*qr + qi*qi;
    const double br = (ar*qr + ai*qi)/qd, bi = (ai*qr - ar*qi)/qd;
    const double sr = k00r - br, sj = k00i - bi;
    Kr[s] = cr*sr - ci*sj;
    Ki[s] = cr*sj + ci*sr;
  }
  const double hr = 0.5*(Kr[0] + Kr[1]);                    // Hermitian part
  const double hi = 0.5*(Ki[0] - Ki[1]);
  const double invL = 1.0 / (double)LL;
  const int rb13 = (int)(__brev((unsigned)f) >> 19);
  khp[layer*LL + rb13] = make_float2((float)((hr + 1.0)*invL), (float)(hi*invL));
}

// ---- fused 4-layer SSM: one block = row pair (packed a+ib), full FFT conv + gelu in LDS
__global__ __launch_bounds__(512) void ssm_fused(const float* __restrict__ uin,
                                                 const float2* __restrict__ khp,
                                                 float* __restrict__ uout) {
  __shared__ float4 lds[4607];   // 4096 float4 units (+1 pad per 8): unit' = u + (u>>3)
  const int t = threadIdx.x;
  const size_t rb = (size_t)blockIdx.x * (2 * LL);
  const float2* u0v = (const float2*)(uin + rb);
  const float2* u1v = (const float2*)(uin + rb + LL);

  float2 v[8][2];                // v[k][c] = element {2t + c + 1024k}
#pragma unroll
  for (int k = 0; k < 8; k++) {
    float2 a = u0v[t + 512*k];
    float2 b = u1v[t + 512*k];
    v[k][0] = make_float2(a.x, b.x);
    v[k][1] = make_float2(a.y, b.y);
  }

  float2 E13[2], E10[2], E7[2];
  {
    const float w13 = -(float)(2.0 * PI_D / 8192.0);
    const float w10 = -(float)(2.0 * PI_D / 1024.0);
    const float w7  = -(float)(2.0 * PI_D / 128.0);
    float r;
    r = (float)(2*t);       sincosf(w13*r, &E13[0].y, &E13[0].x); sincosf(w13*(r+1.0f), &E13[1].y, &E13[1].x);
    r = (float)(2*(t&63));  sincosf(w10*r, &E10[0].y, &E10[0].x); sincosf(w10*(r+1.0f), &E10[1].y, &E10[1].x);
    r = (float)(2*(t&7));   sincosf(w7*r,  &E7[0].y,  &E7[0].x);  sincosf(w7*(r+1.0f),  &E7[1].y,  &E7[1].x);
  }
  const float2 F13[2] = { cconjf(E13[0]), cconjf(E13[1]) };
  const float2 F10[2] = { cconjf(E10[0]), cconjf(E10[1]) };
  const float2 F7[2]  = { cconjf(E7[0]),  cconjf(E7[1])  };

  const int m6 = t & 63;
  const int b1 = t + (t >> 3);                 // pattern {t + 512k} units, stride 576
  const int b2 = 576*(t >> 6) + m6 + (m6 >> 3);// pattern {512g + m + 64k}, stride 72
  const int b3 = 72*(t >> 3) + (t & 7);        // pattern {64g + s + 8k}, stride 9
  const int b4 = 9*t;                          // pattern {8t + j}, stride 1

  const float4* kb = (const float4*)khp;

#pragma unroll 1
  for (int layer = 0; layer < NLAYERS; layer++) {
    // F1: DIF m=8192,4096,2048
    dif3(v, E13);
    __syncthreads();   // protect prev layer's I4 reads
#pragma unroll
    for (int k = 0; k < 8; k++)
      lds[b1 + 576*k] = make_float4(v[k][0].x, v[k][0].y, v[k][1].x, v[k][1].y);
    __syncthreads();
    // F2: m=1024,512,256
#pragma unroll
    for (int k = 0; k < 8; k++) { float4 q = lds[b2 + 72*k]; v[k][0] = make_float2(q.x,q.y); v[k][1] = make_float2(q.z,q.w); }
    dif3(v, E10);
#pragma unroll
    for (int k = 0; k < 8; k++)
      lds[b2 + 72*k] = make_float4(v[k][0].x, v[k][0].y, v[k][1].x, v[k][1].y);
    __syncthreads();
    // F3: m=128,64,32
#pragma unroll
    for (int k = 0; k < 8; k++) { float4 q = lds[b3 + 9*k]; v[k][0] = make_float2(q.x,q.y); v[k][1] = make_float2(q.z,q.w); }
    dif3(v, E7);
#pragma unroll
    for (int k = 0; k < 8; k++)
      lds[b3 + 9*k] = make_float4(v[k][0].x, v[k][0].y, v[k][1].x, v[k][1].y);
    __syncthreads();
    // F45 + pointwise (bit-reversed) + I1
    {
      float2 w[16];
      const float4* kv = kb + (layer << 12) + 8*t;
      float4 kq[8];
#pragma unroll
      for (int k = 0; k < 8; k++) kq[k] = kv[k];
#pragma unroll
      for (int k = 0; k < 8; k++) { float4 q = lds[b4 + k]; w[2*k] = make_float2(q.x,q.y); w[2*k+1] = make_float2(q.z,q.w); }
      fwd4(w);
#pragma unroll
      for (int k = 0; k < 8; k++) {
        w[2*k]   = cmulf(w[2*k],   make_float2(kq[k].x, kq[k].y));
        w[2*k+1] = cmulf(w[2*k+1], make_float2(kq[k].z, kq[k].w));
      }
      inv4(w);
#pragma unroll
      for (int k = 0; k < 8; k++)
        lds[b4 + k] = make_float4(w[2*k].x, w[2*k].y, w[2*k+1].x, w[2*k+1].y);
    }
    __syncthreads();
    // I2: m=32,64,128
#pragma unroll
    for (int k = 0; k < 8; k++) { float4 q = lds[b3 + 9*k]; v[k][0] = make_float2(q.x,q.y); v[k][1] = make_float2(q.z,q.w); }
    dit3(v, F7);
#pragma unroll
    for (int k = 0; k < 8; k++)
      lds[b3 + 9*k] = make_float4(v[k][0].x, v[k][0].y, v[k][1].x, v[k][1].y);
    __syncthreads();
    // I3: m=256,512,1024
#pragma unroll
    for (int k = 0; k < 8; k++) { float4 q = lds[b2 + 72*k]; v[k][0] = make_float2(q.x,q.y); v[k][1] = make_float2(q.z,q.w); }
    dit3(v, F10);
#pragma unroll
    for (int k = 0; k < 8; k++)
      lds[b2 + 72*k] = make_float4(v[k][0].x, v[k][0].y, v[k][1].x, v[k][1].y);
    __syncthreads();
    // I4: m=2048,4096,8192, then GELU (1/L folded into khp)
#pragma unroll
    for (int k = 0; k < 8; k++) { float4 q = lds[b1 + 576*k]; v[k][0] = make_float2(q.x,q.y); v[k][1] = make_float2(q.z,q.w); }
    dit3(v, F13);
#pragma unroll
    for (int k = 0; k < 8; k++)
#pragma unroll
      for (int c = 0; c < 2; c++) {
        v[k][c].x = gelu_exact(v[k][c].x);
        v[k][c].y = gelu_exact(v[k][c].y);
      }
  }

  float2* o0 = (float2*)(uout + rb);
  float2* o1 = (float2*)(uout + rb + LL);
#pragma unroll
  for (int k = 0; k < 8; k++) {
    o0[t + 512*k] = make_float2(v[k][0].x, v[k][1].x);
    o1[t + 512*k] = make_float2(v[k][0].y, v[k][1].y);
  }
}

extern "C" void kernel_launch(void* const* d_in, const int* in_sizes, int n_in,
                              void* d_out, int out_size, void* d_ws, size_t ws_size,
                              hipStream_t stream) {
  const float* u  = (const float*)d_in[0];
  const float* Lr = (const float*)d_in[1];
  const float* Li = (const float*)d_in[2];
  const float* P  = (const float*)d_in[3];
  const float* B  = (const float*)d_in[4];
  const float* C  = (const float*)d_in[5];
  const float* S  = (const float*)d_in[6];
  float2* khp = (float2*)d_ws;  // 4*8192 float2 = 256 KB

  hipLaunchKernelGGL(ssm_setup, dim3(LL/256, NLAYERS), dim3(256), 0, stream,
                     Lr, Li, P, B, C, S, khp);
  hipLaunchKernelGGL(ssm_fused, dim3(4096/2), dim3(512), 0, stream,
                     u, khp, (float*)d_out);
}

// Round 3
// 521.451 us; speedup vs baseline: 1.1952x; 1.1952x over previous
//
#include <hip/hip_runtime.h>
#include <math.h>

#define LL 8192
#define NLAYERS 4
#define NSTATE 64
#define SQ2H 0.70710678118654752f
#define PI_D 3.14159265358979323846

typedef float v2f __attribute__((ext_vector_type(2)));

// packed complex helpers: (X,Y) = (re-pair, im-pair), twiddle (tx,ty)
// forward mul: r = z * t
#define CMULP(rx, ry, zx, zy, tx, ty) { rx = (zx)*(tx) - (zy)*(ty); ry = (zx)*(ty) + (zy)*(tx); }
// conj mul: r = z * conj(t)
#define CMULCP(rx, ry, zx, zy, tx, ty) { rx = (zx)*(tx) + (zy)*(ty); ry = (zy)*(tx) - (zx)*(ty); }

// 3 forward DIF stages (sizes 8S,4S,2S) on 8 packed units (16 elems), t1 = W_{8S}^{2r+lane}
__device__ __forceinline__ void dif3p(v2f X[8], v2f Y[8], v2f t1x, v2f t1y) {
  v2f t2x = t1x*t1x - t1y*t1y, t2y = 2.0f*(t1x*t1y);
  v2f t4x = t2x*t2x - t2y*t2y, t4y = 2.0f*(t2x*t2y);
#pragma unroll
  for (int k = 0; k < 4; k++) {          // m=8S: (k,k+4), tw = C8[k]*t1
    v2f ax = X[k], ay = Y[k], bx = X[k+4], by = Y[k+4];
    X[k] = ax + bx; Y[k] = ay + by;
    v2f dx = ax - bx, dy = ay - by, ex, ey;
    if (k == 0)      { ex = dx; ey = dy; }
    else if (k == 1) { ex = (dx + dy) * SQ2H; ey = (dy - dx) * SQ2H; }
    else if (k == 2) { ex = dy; ey = -dx; }
    else             { ex = (dy - dx) * SQ2H; ey = -((dx + dy) * SQ2H); }
    CMULP(X[k+4], Y[k+4], ex, ey, t1x, t1y);
  }
#pragma unroll
  for (int h = 0; h < 8; h += 4)         // m=4S: (k,k+2), tw = t2*{1,-i}
#pragma unroll
    for (int l = 0; l < 2; l++) {
      int k = h + l;
      v2f ax = X[k], ay = Y[k], bx = X[k+2], by = Y[k+2];
      X[k] = ax + bx; Y[k] = ay + by;
      v2f dx = ax - bx, dy = ay - by, ex, ey;
      CMULP(ex, ey, dx, dy, t2x, t2y);
      if (l == 0) { X[k+2] = ex; Y[k+2] = ey; }
      else        { X[k+2] = ey; Y[k+2] = -ex; }   // * -i
    }
#pragma unroll
  for (int k = 0; k < 8; k += 2) {       // m=2S: (k,k+1), tw = t4
    v2f ax = X[k], ay = Y[k], bx = X[k+1], by = Y[k+1];
    X[k] = ax + bx; Y[k] = ay + by;
    v2f dx = ax - bx, dy = ay - by;
    CMULP(X[k+1], Y[k+1], dx, dy, t4x, t4y);
  }
}

// 3 inverse DIT stages (sizes m1,2m1,4m1), twiddles = conj of forward t1 set
__device__ __forceinline__ void dit3p(v2f X[8], v2f Y[8], v2f t1x, v2f t1y) {
  v2f t2x = t1x*t1x - t1y*t1y, t2y = 2.0f*(t1x*t1y);
  v2f t4x = t2x*t2x - t2y*t2y, t4y = 2.0f*(t2x*t2y);
#pragma unroll
  for (int k = 0; k < 8; k += 2) {       // m1: (k,k+1), b *= conj(t4)
    v2f bx, by;
    CMULCP(bx, by, X[k+1], Y[k+1], t4x, t4y);
    v2f ax = X[k], ay = Y[k];
    X[k] = ax + bx;   Y[k] = ay + by;
    X[k+1] = ax - bx; Y[k+1] = ay - by;
  }
#pragma unroll
  for (int h = 0; h < 8; h += 4)         // 2m1: (k,k+2), b *= conj(t2)*{1,+i}
#pragma unroll
    for (int l = 0; l < 2; l++) {
      int k = h + l;
      v2f bx, by;
      CMULCP(bx, by, X[k+2], Y[k+2], t2x, t2y);
      if (l == 1) { v2f tm = bx; bx = -by; by = tm; }  // * +i
      v2f ax = X[k], ay = Y[k];
      X[k] = ax + bx;   Y[k] = ay + by;
      X[k+2] = ax - bx; Y[k+2] = ay - by;
    }
#pragma unroll
  for (int k = 0; k < 4; k++) {          // 4m1: (k,k+4), b = conj(C8[k])*conj(t1)*b
    v2f cx, cy;
    CMULCP(cx, cy, X[k+4], Y[k+4], t1x, t1y);
    v2f bx, by;
    if (k == 0)      { bx = cx; by = cy; }
    else if (k == 1) { bx = (cx - cy) * SQ2H; by = (cx + cy) * SQ2H; }
    else if (k == 2) { bx = -cy; by = cx; }
    else             { bx = -((cx + cy) * SQ2H); by = (cx - cy) * SQ2H; }
    v2f ax = X[k], ay = Y[k];
    X[k] = ax + bx;   Y[k] = ay + by;
    X[k+4] = ax - bx; Y[k+4] = ay - by;
  }
}

// forward stages m=16,8,4,2 on 8 packed units (16 contiguous elems), const twiddles
__device__ __forceinline__ void fwd4p(v2f X[8], v2f Y[8]) {
  const float c16[8] = {1.f, 0.92387953f, 0.70710678f, 0.38268343f,
                        0.f, -0.38268343f, -0.70710678f, -0.92387953f};
  const float s16[8] = {0.f, -0.38268343f, -0.70710678f, -0.92387953f,
                        -1.f, -0.92387953f, -0.70710678f, -0.38268343f};
#pragma unroll
  for (int k = 0; k < 4; k++) {          // m=16: (k,k+4), tw = W16^{2k+lane}
    v2f tx = {c16[2*k], c16[2*k+1]}, ty = {s16[2*k], s16[2*k+1]};
    v2f ax = X[k], ay = Y[k], bx = X[k+4], by = Y[k+4];
    X[k] = ax + bx; Y[k] = ay + by;
    v2f dx = ax - bx, dy = ay - by;
    CMULP(X[k+4], Y[k+4], dx, dy, tx, ty);
  }
#pragma unroll
  for (int h = 0; h < 8; h += 4)         // m=8: (k,k+2), tw = W8^{2l+lane}
#pragma unroll
    for (int l = 0; l < 2; l++) {
      int k = h + l;
      v2f tx = (l == 0) ? v2f{1.f, SQ2H} : v2f{0.f, -SQ2H};
      v2f ty = (l == 0) ? v2f{0.f, -SQ2H} : v2f{-1.f, -SQ2H};
      v2f ax = X[k], ay = Y[k], bx = X[k+2], by = Y[k+2];
      X[k] = ax + bx; Y[k] = ay + by;
      v2f dx = ax - bx, dy = ay - by;
      CMULP(X[k+2], Y[k+2], dx, dy, tx, ty);
    }
#pragma unroll
  for (int k = 0; k < 8; k += 2) {       // m=4: (k,k+1), tw = {1,-i} per lane
    v2f ax = X[k], ay = Y[k], bx = X[k+1], by = Y[k+1];
    X[k] = ax + bx; Y[k] = ay + by;
    v2f dx = ax - bx, dy = ay - by;
    X[k+1] = v2f{dx.x, dy.y};
    Y[k+1] = v2f{dy.x, -dx.y};
  }
#pragma unroll
  for (int u = 0; u < 8; u++) {          // m=2: cross-lane
    v2f x = X[u], y = Y[u];
    X[u] = v2f{x.x + x.y, x.x - x.y};
    Y[u] = v2f{y.x + y.y, y.x - y.y};
  }
}

// inverse stages m=2,4,8,16
__device__ __forceinline__ void inv4p(v2f X[8], v2f Y[8]) {
  const float c16[8] = {1.f, 0.92387953f, 0.70710678f, 0.38268343f,
                        0.f, -0.38268343f, -0.70710678f, -0.92387953f};
  const float s16[8] = {0.f, -0.38268343f, -0.70710678f, -0.92387953f,
                        -1.f, -0.92387953f, -0.70710678f, -0.38268343f};
#pragma unroll
  for (int u = 0; u < 8; u++) {          // m=2: cross-lane
    v2f x = X[u], y = Y[u];
    X[u] = v2f{x.x + x.y, x.x - x.y};
    Y[u] = v2f{y.x + y.y, y.x - y.y};
  }
#pragma unroll
  for (int k = 0; k < 8; k += 2) {       // m=4: (k,k+1), b *= {1,+i} per lane
    v2f bx0 = X[k+1], by0 = Y[k+1];
    v2f bx = v2f{bx0.x, -by0.y};
    v2f by = v2f{by0.x, bx0.y};
    v2f ax = X[k], ay = Y[k];
    X[k] = ax + bx;   Y[k] = ay + by;
    X[k+1] = ax - bx; Y[k+1] = ay - by;
  }
#pragma unroll
  for (int h = 0; h < 8; h += 4)         // m=8: (k,k+2), b *= conj(W8^{2l+lane})
#pragma unroll
    for (int l = 0; l < 2; l++) {
      int k = h + l;
      v2f tx = (l == 0) ? v2f{1.f, SQ2H} : v2f{0.f, -SQ2H};
      v2f ty = (l == 0) ? v2f{0.f, -SQ2H} : v2f{-1.f, -SQ2H};
      v2f bx, by;
      CMULCP(bx, by, X[k+2], Y[k+2], tx, ty);
      v2f ax = X[k], ay = Y[k];
      X[k] = ax + bx;   Y[k] = ay + by;
      X[k+2] = ax - bx; Y[k+2] = ay - by;
    }
#pragma unroll
  for (int k = 0; k < 4; k++) {          // m=16: (k,k+4), b *= conj(W16^{2k+lane})
    v2f tx = {c16[2*k], c16[2*k+1]}, ty = {s16[2*k], s16[2*k+1]};
    v2f bx, by;
    CMULCP(bx, by, X[k+4], Y[k+4], tx, ty);
    v2f ax = X[k], ay = Y[k];
    X[k] = ax + bx;   Y[k] = ay + by;
    X[k+4] = ax - bx; Y[k+4] = ay - by;
  }
}

__device__ __forceinline__ float gelu_exact(float x) {
  return 0.5f * x * (1.0f + erff(x * 0.70710678118654752f));
}

// ---- setup: khp float4 units (re_e, re_o, im_e, im_o), bins in bitrev13 order,
// value = (Kh(f)+1)/L ; each thread computes f in [0,4096] and writes f and L-f (conj)
__global__ void ssm_setup(const float* __restrict__ Lr, const float* __restrict__ Li,
                          const float* __restrict__ Pv, const float* __restrict__ Bv,
                          const float* __restrict__ Cv, const float* __restrict__ Sv,
                          float* __restrict__ khp) {
  const int f = blockIdx.x * blockDim.x + threadIdx.x;
  const int layer = blockIdx.y;
  if (f > LL/2) return;
  const double step = (double)Sv[layer];
  const float* lr = Lr + layer * NSTATE;
  const float* li = Li + layer * NSTATE;
  const float* pp = Pv + layer * NSTATE;
  const float* bb = Bv + layer * NSTATE;
  const float* ct = Cv + layer * NSTATE;
  const double ts = 2.0 / step;

  double Kr[2], Ki[2];
  const int f2[2] = { f, (LL - f) & (LL - 1) };
#pragma unroll 1
  for (int s = 0; s < 2; s++) {
    const double th = -2.0 * PI_D * (double)f2[s] / (double)LL;
    const double co = cos(th), si = sin(th);
    const double pr = 1.0 + co, pim = si;
    const double pd = pr*pr + pim*pim;
    const double rpd = 1.0 / pd;
    const double cr = 2.0*pr*rpd, ci = -2.0*pim*rpd;        // c = 2/(1+Om)
    const double mr = 1.0 - co, mi = -si;
    const double gr = ts*(mr*pr + mi*pim)*rpd;              // g = ts*(1-Om)/(1+Om)
    const double gi = ts*(mi*pr - mr*pim)*rpd;
    double k00r=0,k00i=0,k01r=0,k01i=0,k10r=0,k10i=0,k11r=0,k11i=0;
    for (int n = 0; n < NSTATE; n++) {
      const double dr = gr - (double)lr[n];
      const double di = gi - (double)li[n];
      const double rd = 1.0 / (dr*dr + di*di);
      const double ir = dr*rd, ii = -di*rd;                 // 1/denom
      const double p = (double)pp[n], b = (double)bb[n], c = (double)ct[n];
      double w;
      w = c*b; k00r += w*ir; k00i += w*ii;
      w = c*p; k01r += w*ir; k01i += w*ii;
      w = p*b; k10r += w*ir; k10i += w*ii;
      w = p*p; k11r += w*ir; k11i += w*ii;
    }
    const double ar = k01r*k10r - k01i*k10i;
    const double ai = k01r*k10i + k01i*k10r;
    const double qr = 1.0 + k11r, qi = k11i;
    const double rqd = 1.0 / (qr*qr + qi*qi);
    const double br = (ar*qr + ai*qi)*rqd, bi = (ai*qr - ar*qi)*rqd;
    const double sr = k00r - br, sj = k00i - bi;
    Kr[s] = cr*sr - ci*sj;
    Ki[s] = cr*sj + ci*sr;
  }
  const double hr = 0.5*(Kr[0] + Kr[1]);                    // Hermitian part
  const double hi = 0.5*(Ki[0] - Ki[1]);
  const double invL = 1.0 / (double)LL;
  const float re = (float)((hr + 1.0)*invL);
  const float im = (float)(hi*invL);
  const int i0 = (int)(__brev((unsigned)f) >> 19);
  const int i1 = (int)(__brev((unsigned)f2[1]) >> 19);
  float* kl = khp + layer * (LL * 2);                       // 16384 floats per layer
  kl[(i0 >> 1)*4 + (i0 & 1)]     = re;                      // bin f
  kl[(i0 >> 1)*4 + 2 + (i0 & 1)] = im;
  kl[(i1 >> 1)*4 + (i1 & 1)]     = re;                      // bin L-f = conj
  kl[(i1 >> 1)*4 + 2 + (i1 & 1)] = -im;
}

// ---- fused 4-layer SSM, packed-fp32 layout:
// unit u holds complex elements (2u, 2u+1); X = re pair, Y = im pair.
__global__ __launch_bounds__(512, 4) void ssm_fused(const float* __restrict__ uin,
                                                    const float* __restrict__ khp,
                                                    float* __restrict__ uout) {
  __shared__ float4 lds[4607];   // 4096 float4 units (+1 pad per 8)
  const int t = threadIdx.x;
  const size_t rb = (size_t)blockIdx.x * (2 * LL);
  const v2f* p0 = (const v2f*)(uin + rb);
  const v2f* p1 = (const v2f*)(uin + rb + LL);

  v2f X[8], Y[8];                // unit index t + 512k
#pragma unroll
  for (int k = 0; k < 8; k++) {
    X[k] = p0[t + 512*k];
    Y[k] = p1[t + 512*k];
  }

  v2f e13x, e13y, e10x, e10y, e7x, e7y;
  {
    const float w13 = -(float)(2.0 * PI_D / 8192.0);
    const float w10 = -(float)(2.0 * PI_D / 1024.0);
    const float w7  = -(float)(2.0 * PI_D / 128.0);
    float c0, s0, c1, s1, r;
    r = (float)(2*t);       sincosf(w13*r, &s0, &c0); sincosf(w13*(r+1.0f), &s1, &c1);
    e13x = v2f{c0, c1}; e13y = v2f{s0, s1};
    r = (float)(2*(t&63));  sincosf(w10*r, &s0, &c0); sincosf(w10*(r+1.0f), &s1, &c1);
    e10x = v2f{c0, c1}; e10y = v2f{s0, s1};
    r = (float)(2*(t&7));   sincosf(w7*r, &s0, &c0);  sincosf(w7*(r+1.0f), &s1, &c1);
    e7x = v2f{c0, c1};  e7y = v2f{s0, s1};
  }

  const int m6 = t & 63;
  const int b1 = t + (t >> 3);                  // {t + 512k} units, stride 576
  const int b2 = 576*(t >> 6) + m6 + (m6 >> 3); // {512g + m + 64k}, stride 72
  const int b3 = 72*(t >> 3) + (t & 7);         // {64g + s + 8k}, stride 9
  const int b4 = 9*t;                           // {8t + j}, stride 1

  const float4* kb = (const float4*)khp;

#pragma unroll 1
  for (int layer = 0; layer < NLAYERS; layer++) {
    // F1: DIF m=8192,4096,2048
    dif3p(X, Y, e13x, e13y);
    __syncthreads();   // protect prev layer's I4 reads
#pragma unroll
    for (int k = 0; k < 8; k++)
      lds[b1 + 576*k] = make_float4(X[k].x, X[k].y, Y[k].x, Y[k].y);
    __syncthreads();
    // F2: m=1024,512,256
#pragma unroll
    for (int k = 0; k < 8; k++) { float4 q = lds[b2 + 72*k]; X[k] = v2f{q.x,q.y}; Y[k] = v2f{q.z,q.w}; }
    dif3p(X, Y, e10x, e10y);
#pragma unroll
    for (int k = 0; k < 8; k++)
      lds[b2 + 72*k] = make_float4(X[k].x, X[k].y, Y[k].x, Y[k].y);
    __syncthreads();
    // F3: m=128,64,32
#pragma unroll
    for (int k = 0; k < 8; k++) { float4 q = lds[b3 + 9*k]; X[k] = v2f{q.x,q.y}; Y[k] = v2f{q.z,q.w}; }
    dif3p(X, Y, e7x, e7y);
#pragma unroll
    for (int k = 0; k < 8; k++)
      lds[b3 + 9*k] = make_float4(X[k].x, X[k].y, Y[k].x, Y[k].y);
    __syncthreads();
    // F45 + pointwise (bit-reversed) + I1
    {
      float4 kq[8];
      const float4* kv = kb + (layer << 12) + 8*t;
#pragma unroll
      for (int k = 0; k < 8; k++) kq[k] = kv[k];
      v2f MX[8], MY[8];
#pragma unroll
      for (int k = 0; k < 8; k++) { float4 q = lds[b4 + k]; MX[k] = v2f{q.x,q.y}; MY[k] = v2f{q.z,q.w}; }
      fwd4p(MX, MY);
#pragma unroll
      for (int k = 0; k < 8; k++) {
        v2f kx = {kq[k].x, kq[k].y}, ky = {kq[k].z, kq[k].w};
        v2f nx, ny;
        CMULP(nx, ny, MX[k], MY[k], kx, ky);
        MX[k] = nx; MY[k] = ny;
      }
      inv4p(MX, MY);
#pragma unroll
      for (int k = 0; k < 8; k++)
        lds[b4 + k] = make_float4(MX[k].x, MX[k].y, MY[k].x, MY[k].y);
    }
    __syncthreads();
    // I2: m=32,64,128
#pragma unroll
    for (int k = 0; k < 8; k++) { float4 q = lds[b3 + 9*k]; X[k] = v2f{q.x,q.y}; Y[k] = v2f{q.z,q.w}; }
    dit3p(X, Y, e7x, e7y);
#pragma unroll
    for (int k = 0; k < 8; k++)
      lds[b3 + 9*k] = make_float4(X[k].x, X[k].y, Y[k].x, Y[k].y);
    __syncthreads();
    // I3: m=256,512,1024
#pragma unroll
    for (int k = 0; k < 8; k++) { float4 q = lds[b2 + 72*k]; X[k] = v2f{q.x,q.y}; Y[k] = v2f{q.z,q.w}; }
    dit3p(X, Y, e10x, e10y);
#pragma unroll
    for (int k = 0; k < 8; k++)
      lds[b2 + 72*k] = make_float4(X[k].x, X[k].y, Y[k].x, Y[k].y);
    __syncthreads();
    // I4: m=2048,4096,8192, then GELU (1/L folded into khp)
#pragma unroll
    for (int k = 0; k < 8; k++) { float4 q = lds[b1 + 576*k]; X[k] = v2f{q.x,q.y}; Y[k] = v2f{q.z,q.w}; }
    dit3p(X, Y, e13x, e13y);
#pragma unroll
    for (int k = 0; k < 8; k++) {
      X[k].x = gelu_exact(X[k].x); X[k].y = gelu_exact(X[k].y);
      Y[k].x = gelu_exact(Y[k].x); Y[k].y = gelu_exact(Y[k].y);
    }
  }

  v2f* o0 = (v2f*)(uout + rb);
  v2f* o1 = (v2f*)(uout + rb + LL);
#pragma unroll
  for (int k = 0; k < 8; k++) {
    o0[t + 512*k] = X[k];
    o1[t + 512*k] = Y[k];
  }
}

extern "C" void kernel_launch(void* const* d_in, const int* in_sizes, int n_in,
                              void* d_out, int out_size, void* d_ws, size_t ws_size,
                              hipStream_t stream) {
  const float* u  = (const float*)d_in[0];
  const float* Lr = (const float*)d_in[1];
  const float* Li = (const float*)d_in[2];
  const float* P  = (const float*)d_in[3];
  const float* B  = (const float*)d_in[4];
  const float* C  = (const float*)d_in[5];
  const float* S  = (const float*)d_in[6];
  float* khp = (float*)d_ws;  // 4 layers * 16384 floats = 256 KB

  hipLaunchKernelGGL(ssm_setup, dim3((LL/2 + 256) / 256, NLAYERS), dim3(256), 0, stream,
                     Lr, Li, P, B, C, S, khp);
  hipLaunchKernelGGL(ssm_fused, dim3(4096/2), dim3(512), 0, stream,
                     u, khp, (float*)d_out);
}